// Round 1
// baseline (474.455 us; speedup 1.0000x reference)
//
#include <hip/hip_runtime.h>

typedef short v8s __attribute__((ext_vector_type(8)));
typedef float v4f __attribute__((ext_vector_type(4)));

__device__ __forceinline__ unsigned short f2bf(float f) {
  union { float f; unsigned u; } x; x.f = f;
  unsigned r = x.u + 0x7fffu + ((x.u >> 16) & 1u);
  return (unsigned short)(r >> 16);
}

__device__ __forceinline__ void cvt16(const float* __restrict__ src, unsigned short* dst) {
  const float4* p = (const float4*)src;
  float4 a = p[0], b = p[1], c = p[2], d = p[3];
  dst[0] = f2bf(a.x);  dst[1] = f2bf(a.y);  dst[2] = f2bf(a.z);  dst[3] = f2bf(a.w);
  dst[4] = f2bf(b.x);  dst[5] = f2bf(b.y);  dst[6] = f2bf(b.z);  dst[7] = f2bf(b.w);
  dst[8] = f2bf(c.x);  dst[9] = f2bf(c.y);  dst[10] = f2bf(c.z); dst[11] = f2bf(c.w);
  dst[12] = f2bf(d.x); dst[13] = f2bf(d.y); dst[14] = f2bf(d.z); dst[15] = f2bf(d.w);
}

// =====================================================================
// GEMM: C[M,512] = A[M,512] @ W[512,512]^T   (BM=BN=128, BK=32, 4 waves)
// MODE 0: A = fp32 (x rows [0,rows0) then support), C = bf16, Q-rows scaled.
// MODE 1: A = bf16 (OT flat), C = fp32 + bias.
// =====================================================================
template <int MODE>
__launch_bounds__(256)
__global__ void gemm_bt_kernel(const float* __restrict__ A0,
                               const float* __restrict__ A1, int rows0,
                               const unsigned short* __restrict__ Abf,
                               const float* __restrict__ Wsrc,
                               const float* __restrict__ bias,
                               unsigned short* __restrict__ Cb,
                               float* __restrict__ Cf, float scale) {
  __shared__ __align__(16) char smem[(MODE == 1) ? 65536 : 32768];
  const int tid = threadIdx.x;
  const int wave = tid >> 6, lane = tid & 63, lr = lane & 15, lg = lane >> 4;
  const int mb = blockIdx.x >> 2, nb = blockIdx.x & 3;
  const int wr = wave >> 1, wc = wave & 1;

  v4f acc[4][4];
#pragma unroll
  for (int i = 0; i < 4; ++i)
#pragma unroll
    for (int j = 0; j < 4; ++j) acc[i][j] = (v4f){0.f, 0.f, 0.f, 0.f};

  const int srow = tid >> 1, kh = tid & 1;
  const size_t arow = (size_t)mb * 128 + srow;
  const float* asrcf = nullptr;
  const unsigned short* asrcb = nullptr;
  if constexpr (MODE == 0) {
    asrcf = (arow < (size_t)rows0) ? (A0 + arow * 512) : (A1 + (arow - (size_t)rows0) * 512);
  } else {
    asrcb = Abf + arow * 512;
  }
  const float* bsrcf = Wsrc + ((size_t)nb * 128 + srow) * 512;
  // staging LDS addresses (64B rows, XOR swizzle on 16B slots)
  const int wa0 = srow * 64 + ((kh * 32) ^ ((srow & 3) << 4));
  const int wa1 = srow * 64 + (((kh * 32) + 16) ^ ((srow & 3) << 4));

  for (int kt = 0; kt < 16; ++kt) {
    const int kbase = kt * 32 + kh * 16;
    __syncthreads();
    unsigned short ta[16], tb[16];
    if constexpr (MODE == 0) {
      cvt16(asrcf + kbase, ta);
    } else {
      const v8s* ap = (const v8s*)(asrcb + kbase);
      *(v8s*)&ta[0] = ap[0];
      *(v8s*)&ta[8] = ap[1];
    }
    cvt16(bsrcf + kbase, tb);
    *(v8s*)&smem[wa0] = *(const v8s*)&ta[0];
    *(v8s*)&smem[wa1] = *(const v8s*)&ta[8];
    *(v8s*)&smem[8192 + wa0] = *(const v8s*)&tb[0];
    *(v8s*)&smem[8192 + wa1] = *(const v8s*)&tb[8];
    __syncthreads();

    v8s af[4], bfr[4];
    const int fo = (lg * 16) ^ ((lr & 3) << 4);
#pragma unroll
    for (int mi = 0; mi < 4; ++mi)
      af[mi] = *(const v8s*)&smem[(wr * 64 + mi * 16 + lr) * 64 + fo];
#pragma unroll
    for (int ni = 0; ni < 4; ++ni)
      bfr[ni] = *(const v8s*)&smem[8192 + (wc * 64 + ni * 16 + lr) * 64 + fo];
    // swapped operands: lane col (lane&15) = M-row, regs walk N -> C[m][n..n+3]
#pragma unroll
    for (int mi = 0; mi < 4; ++mi)
#pragma unroll
      for (int ni = 0; ni < 4; ++ni)
        acc[mi][ni] = __builtin_amdgcn_mfma_f32_16x16x32_bf16(bfr[ni], af[mi], acc[mi][ni], 0, 0, 0);
  }

  __syncthreads();
  if constexpr (MODE == 0) {
#pragma unroll
    for (int mi = 0; mi < 4; ++mi) {
      const int ml = wr * 64 + mi * 16 + lr;
      const float sc = ((size_t)mb * 128 + ml < (size_t)rows0) ? scale : 1.0f;
#pragma unroll
      for (int ni = 0; ni < 4; ++ni) {
        const int nl = wc * 64 + ni * 16 + lg * 4;
        ushort4 pk;
        pk.x = f2bf(acc[mi][ni][0] * sc);
        pk.y = f2bf(acc[mi][ni][1] * sc);
        pk.z = f2bf(acc[mi][ni][2] * sc);
        pk.w = f2bf(acc[mi][ni][3] * sc);
        *(ushort4*)&smem[ml * 256 + ((nl * 2) ^ ((ml & 7) << 4))] = pk;
      }
    }
    __syncthreads();
#pragma unroll
    for (int p = 0; p < 8; ++p) {
      const int row = p * 16 + (tid >> 4);
      const int off = (tid & 15) * 16;
      v8s v = *(const v8s*)&smem[row * 256 + (off ^ ((row & 7) << 4))];
      *(v8s*)(Cb + ((size_t)mb * 128 + row) * 512 + nb * 128 + (tid & 15) * 8) = v;
    }
  } else {
#pragma unroll
    for (int mi = 0; mi < 4; ++mi) {
      const int ml = wr * 64 + mi * 16 + lr;
#pragma unroll
      for (int ni = 0; ni < 4; ++ni) {
        const int nl = wc * 64 + ni * 16 + lg * 4;
        *(float4*)&smem[ml * 512 + ((nl * 4) ^ ((ml & 7) << 4))] =
            (float4){acc[mi][ni][0], acc[mi][ni][1], acc[mi][ni][2], acc[mi][ni][3]};
      }
    }
    __syncthreads();
    const float4 bb = *(const float4*)(bias + nb * 128 + (tid & 31) * 4);
#pragma unroll
    for (int p = 0; p < 16; ++p) {
      const int row = p * 8 + (tid >> 5);
      const int off = (tid & 31) * 16;
      float4 v = *(const float4*)&smem[row * 512 + (off ^ ((row & 7) << 4))];
      v.x += bb.x; v.y += bb.y; v.z += bb.z; v.w += bb.w;
      *(float4*)(Cf + ((size_t)mb * 128 + row) * 512 + nb * 128 + (tid & 31) * 4) = v;
    }
  }
}

// =====================================================================
// Transpose: Kb [B*4096,512] bf16 -> KT [B][512][4096] bf16
// =====================================================================
__global__ __launch_bounds__(256) void transpose_k(const unsigned short* __restrict__ Kb,
                                                   unsigned short* __restrict__ KT) {
  __shared__ unsigned short tile[64][65];
  const int b = blockIdx.z, cb = blockIdx.y * 64, mb = blockIdx.x * 64;
  const int tid = threadIdx.x;
#pragma unroll
  for (int i = 0; i < 16; ++i) {
    const int e = i * 256 + tid;
    const int ml = e >> 6, cl = e & 63;
    tile[ml][cl] = Kb[((size_t)b * 4096 + mb + ml) * 512 + cb + cl];
  }
  __syncthreads();
#pragma unroll
  for (int i = 0; i < 16; ++i) {
    const int e = i * 256 + tid;
    const int cl = e >> 6, ml = e & 63;
    KT[((size_t)b * 512 + cb + cl) * 4096 + mb + ml] = tile[ml][cl];
  }
}

// =====================================================================
// Flash attention: 4 waves x 16 queries, KBLK=32, d=512.
// S = Q*K^T (scale folded into Q). Online softmax, deferred rescale.
// Denominator includes masked keys; P zeroed by mask before PV (per ref).
// Output stored TRANSPOSED: OT[b][c][n].
// LDS: K tile [32][1024B] swz @0 (P tiles aliased in, extra barrier),
//      VT tile [512][64B] swz @32768, O-bounce [c][q] reuses all 64KB.
// =====================================================================
__launch_bounds__(256)
__global__ void attn_kernel(const unsigned short* __restrict__ Qb,
                            const unsigned short* __restrict__ Kall,
                            const unsigned short* __restrict__ KT,
                            const int* __restrict__ amask,
                            unsigned short* __restrict__ OT) {
  __shared__ __align__(16) char smem[65536];
  const int tid = threadIdx.x, wave = tid >> 6, lane = tid & 63;
  const int lr = lane & 15, lg = lane >> 4;
  const int b = blockIdx.x >> 6;
  const int qb0 = (blockIdx.x & 63) * 64;

  // Q fragments: lane holds row (qb0+wave*16+lr), 8 elems at cs*32+lg*8
  const unsigned short* Qrow = Qb + ((size_t)b * 4096 + qb0 + wave * 16 + lr) * 512;
  v8s qf[16];
#pragma unroll
  for (int cs = 0; cs < 16; ++cs) qf[cs] = *(const v8s*)(Qrow + cs * 32 + lg * 8);

  v4f o[32];
#pragma unroll
  for (int i = 0; i < 32; ++i) o[i] = (v4f){0.f, 0.f, 0.f, 0.f};
  float mrun[4] = {-3e38f, -3e38f, -3e38f, -3e38f};
  float lsum[4] = {0.f, 0.f, 0.f, 0.f};

  const unsigned short* Kbb = Kall + (size_t)b * 4096 * 512;
  const unsigned short* KTb = KT + (size_t)b * 512 * 4096;
  const int Pbase = wave * 1024;  // aliases K-tile rows, guarded by barrier

#pragma unroll 1
  for (int kb = 0; kb < 4096; kb += 32) {
    __syncthreads();  // prev iter reads (K,VT,P) done
    // ---- stage K tile: rows=key, 1KB rows, 16B-slot XOR swizzle by key&7
#pragma unroll
    for (int i = 0; i < 8; ++i) {
      const int ci = i * 256 + tid;
      const int key = ci >> 6, s16 = ci & 63;
      v8s v = *(const v8s*)(Kbb + (size_t)(kb + key) * 512 + s16 * 8);
      *(v8s*)&smem[key * 1024 + ((s16 * 16) ^ ((key & 7) << 4))] = v;
    }
    // ---- stage VT tile: rows=channel (64B), swizzle by (c>>1)&3
#pragma unroll
    for (int i = 0; i < 8; ++i) {
      const int ci = i * 256 + tid;
      const int c = ci >> 2, sq = ci & 3;
      v8s v = *(const v8s*)(KTb + (size_t)c * 4096 + kb + sq * 8);
      *(v8s*)&smem[32768 + c * 64 + ((sq * 16) ^ (((c >> 1) & 3) << 4))] = v;
    }
    __syncthreads();

    // ---- QK^T: S frag col=key(lane&15), rows=q(lg*4+r)
    v4f s0 = (v4f){0.f, 0.f, 0.f, 0.f}, s1 = (v4f){0.f, 0.f, 0.f, 0.f};
#pragma unroll
    for (int cs = 0; cs < 16; ++cs) {
      const int yb = cs * 64 + lg * 16;
      v8s k0 = *(const v8s*)&smem[lr * 1024 + (yb ^ ((lr & 7) << 4))];
      v8s k1 = *(const v8s*)&smem[(lr + 16) * 1024 + (yb ^ ((lr & 7) << 4))];
      s0 = __builtin_amdgcn_mfma_f32_16x16x32_bf16(qf[cs], k0, s0, 0, 0, 0);
      s1 = __builtin_amdgcn_mfma_f32_16x16x32_bf16(qf[cs], k1, s1, 0, 0, 0);
    }
    __syncthreads();  // all waves done reading K tile (P aliases it)

    // ---- online softmax
    float tmax[4];
#pragma unroll
    for (int r = 0; r < 4; ++r) tmax[r] = fmaxf(s0[r], s1[r]);
#pragma unroll
    for (int msk = 1; msk < 16; msk <<= 1)
#pragma unroll
      for (int r = 0; r < 4; ++r) tmax[r] = fmaxf(tmax[r], __shfl_xor(tmax[r], msk));
    bool need = false;
#pragma unroll
    for (int r = 0; r < 4; ++r) need = need || (tmax[r] > mrun[r] + 8.0f);
    if (__any(need)) {
      v4f sfv;
#pragma unroll
      for (int r = 0; r < 4; ++r) {
        const float nm = fmaxf(mrun[r], tmax[r]);
        const float sf = __expf(mrun[r] - nm);
        lsum[r] *= sf;
        mrun[r] = nm;
        sfv[r] = sf;
      }
#pragma unroll
      for (int i = 0; i < 32; ++i) o[i] *= sfv;
    }
    const int mk0 = amask[kb + lr];
    const int mk1 = amask[kb + 16 + lr];
#pragma unroll
    for (int r = 0; r < 4; ++r) {
      float p0 = __expf(s0[r] - mrun[r]);
      float p1 = __expf(s1[r] - mrun[r]);
      lsum[r] += p0 + p1;  // denominator BEFORE masking (ref: mask post-softmax)
      if (mk0 == 0) p0 = 0.f;
      if (mk1 == 0) p1 = 0.f;
      const int q = lg * 4 + r;
      *(unsigned short*)&smem[Pbase + q * 64 + lr * 2] = f2bf(p0);
      *(unsigned short*)&smem[Pbase + q * 64 + 32 + lr * 2] = f2bf(p1);
    }
    // ---- PV: A=P (reused across all 32 c-tiles), B=VT frags
    v8s pf = *(const v8s*)&smem[Pbase + lr * 64 + lg * 16];
#pragma unroll
    for (int ct = 0; ct < 32; ++ct) {
      const int c = ct * 16 + lr;
      v8s vf = *(const v8s*)&smem[32768 + c * 64 + ((lg * 16) ^ (((c >> 1) & 3) << 4))];
      o[ct] = __builtin_amdgcn_mfma_f32_16x16x32_bf16(pf, vf, o[ct], 0, 0, 0);
    }
  }

  // ---- finalize: reduce lsum across the 16 key-lanes, normalize
#pragma unroll
  for (int msk = 1; msk < 16; msk <<= 1)
#pragma unroll
    for (int r = 0; r < 4; ++r) lsum[r] += __shfl_xor(lsum[r], msk);
  float inv[4];
#pragma unroll
  for (int r = 0; r < 4; ++r) inv[r] = 1.0f / lsum[r];

  __syncthreads();  // everyone done with loop LDS
  // O bounce: per-wave [512 c][16 q] region (16KB), then coalesced OT store
  const int obase = wave * 16384;
#pragma unroll
  for (int ct = 0; ct < 32; ++ct)
#pragma unroll
    for (int r = 0; r < 4; ++r)
      *(unsigned short*)&smem[obase + (ct * 16 + lr) * 32 + (lg * 4 + r) * 2] =
          f2bf(o[ct][r] * inv[r]);
  __syncthreads();
  unsigned short* OTb = OT + (size_t)b * 512 * 4096 + qb0;
#pragma unroll
  for (int p = 0; p < 32; ++p) {
    const int c = p * 16 + (tid >> 4);
    const int q4 = (tid & 15) * 4;
    const int w = q4 >> 4, ql = q4 & 15;
    ushort4 pk = *(const ushort4*)&smem[w * 16384 + c * 32 + ql * 2];
    *(ushort4*)(OTb + (size_t)c * 4096 + q4) = pk;
  }
}

// =====================================================================
extern "C" void kernel_launch(void* const* d_in, const int* in_sizes, int n_in,
                              void* d_out, int out_size, void* d_ws, size_t ws_size,
                              hipStream_t stream) {
  (void)in_sizes; (void)n_in; (void)out_size; (void)ws_size;
  const float* x = (const float*)d_in[0];
  const float* sup = (const float*)d_in[1];
  const int* amask = (const int*)d_in[2];
  const float* Wv = (const float*)d_in[3];
  const float* Wp = (const float*)d_in[4];
  const float* bp = (const float*)d_in[5];
  float* out = (float*)d_out;

  char* ws = (char*)d_ws;
  unsigned short* QKb = (unsigned short*)ws;                          // 32768x512 bf16 (Q rows, then K rows)
  unsigned short* KT = (unsigned short*)(ws + (size_t)33554432);      // [4][512][4096] bf16
  unsigned short* OT = (unsigned short*)(ws + (size_t)50331648);      // [4][512][4096] bf16
  unsigned short* Kb = QKb + (size_t)16384 * 512;

  // 1) Q|K = [x;support] @ Wv^T (bf16; Q rows pre-scaled by 0.125 — exact pow2)
  gemm_bt_kernel<0><<<dim3(1024), dim3(256), 0, stream>>>(
      x, sup, 16384, nullptr, Wv, nullptr, QKb, nullptr, 0.125f);
  // 2) KT = K^T per batch
  transpose_k<<<dim3(64, 8, 4), dim3(256), 0, stream>>>(Kb, KT);
  // 3) flash attention -> OT (transposed output == reference's transpose+reshape)
  attn_kernel<<<dim3(256), dim3(256), 0, stream>>>(QKb, Kb, KT, amask, OT);
  // 4) out = OT_flat @ Wp^T + bp (fp32)
  gemm_bt_kernel<1><<<dim3(512), dim3(256), 0, stream>>>(
      nullptr, nullptr, 0, OT, Wp, bp, nullptr, out, 1.0f);
}